// Round 1
// baseline (161.976 us; speedup 1.0000x reference)
//
#include <hip/hip_runtime.h>

// retinex_synthesis: out = clip(expm1(log1p(ins) + blur(log1p(bg) - log1p(ins))), 0, 1)
// blur = depthwise 31x31 Gaussian (sigma=5), SAME zero padding, separable g (x) g.
// Restructured: ONE separable blur of d = log1p(bg) - log1p(ins)  (conv is linear).

constexpr int W_    = 512;
constexpr int H_    = 512;
constexpr int NIMG  = 48;            // B*C = 16*3
constexpr int NROWS = NIMG * H_;     // 24576

// Normalized Gaussian(sigma=5, ksize=31); double-precision derived, matches the
// reference's float32 build to ~1e-7 relative (absmax threshold is 2e-2).
__device__ constexpr float G[31] = {
    8.8805851e-04f, 1.5861066e-03f, 2.7217699e-03f, 4.4874399e-03f,
    7.1084368e-03f, 1.0818767e-02f, 1.5820117e-02f, 2.2226435e-02f,
    3.0002549e-02f, 3.8911209e-02f, 4.8486352e-02f, 5.8048702e-02f,
    6.6771901e-02f, 7.3794364e-02f, 7.8357552e-02f, 7.9940480e-02f,
    7.8357552e-02f, 7.3794364e-02f, 6.6771901e-02f, 5.8048702e-02f,
    4.8486352e-02f, 3.8911209e-02f, 3.0002549e-02f, 2.2226435e-02f,
    1.5820117e-02f, 1.0818767e-02f, 7.1084368e-03f, 4.4874399e-03f,
    2.7217699e-03f, 1.5861066e-03f, 8.8805851e-04f};

// Kernel 1: per row — d = log1p(bg)-log1p(ins), horizontal 31-tap blur -> tmp.
// 128 threads/block, one block per row; each thread -> 4 consecutive outputs.
// NOTE: bg/tmp intentionally NOT __restrict__ (tmp may alias bg in the ws
// fallback; per-block read-into-LDS + barrier precedes any store, rows disjoint).
__global__ __launch_bounds__(128) void hblur(const float* bg,
                                             const float* __restrict__ ins,
                                             float* tmp) {
  __shared__ __align__(16) float sh[544];   // x in [-16, 528), zero-padded halo
  const int tid = threadIdx.x;
  const size_t base = (size_t)blockIdx.x * W_;

  float4* s4w = (float4*)sh;
  if (tid < 8) {
    int s = (tid < 4) ? tid : (128 + tid);  // slots 0..3 and 132..135 = pad
    s4w[s] = make_float4(0.f, 0.f, 0.f, 0.f);
  }
  {
    float4 b = ((const float4*)(bg + base))[tid];
    float4 n = ((const float4*)(ins + base))[tid];
    float4 v;
    v.x = __logf(1.f + b.x) - __logf(1.f + n.x);
    v.y = __logf(1.f + b.y) - __logf(1.f + n.y);
    v.z = __logf(1.f + b.z) - __logf(1.f + n.z);
    v.w = __logf(1.f + b.w) - __logf(1.f + n.w);
    s4w[tid + 4] = v;                       // slot tid+4 covers gx = 4*tid..4*tid+3
  }
  __syncthreads();

  // window: sh[4*tid .. 4*tid+35]  (global x in [x0-16, x0+20)), 9 x ds_read_b128
  float win[36];
  const float4* s4 = (const float4*)sh;
#pragma unroll
  for (int k = 0; k < 9; ++k) {
    float4 v = s4[tid + k];
    win[4 * k + 0] = v.x; win[4 * k + 1] = v.y;
    win[4 * k + 2] = v.z; win[4 * k + 3] = v.w;
  }
  // output x0+p uses taps win[p+1+c], c=0..30
  float4 acc = make_float4(0.f, 0.f, 0.f, 0.f);
#pragma unroll
  for (int c = 0; c < 31; ++c) {
    acc.x += G[c] * win[1 + c];
    acc.y += G[c] * win[2 + c];
    acc.z += G[c] * win[3 + c];
    acc.w += G[c] * win[4 + c];
  }
  ((float4*)(tmp + base))[tid] = acc;
}

// Kernel 2: vertical 31-tap blur of tmp + fused epilogue.
// Block (64,4): 64 cols x 4 row-groups; each thread accumulates 8 output rows
// from a 38-row sliding input window (register accumulators, constant coeffs).
__global__ __launch_bounds__(256) void vblur(const float* __restrict__ tmp,
                                             const float* __restrict__ ins,
                                             float* __restrict__ out) {
  const int tx = threadIdx.x;                       // 0..63
  const int x  = blockIdx.x * 64 + tx;              // 0..511
  const int y0 = blockIdx.y * 32 + threadIdx.y * 8; // 0..504 step 8
  const size_t base = (size_t)blockIdx.z * ((size_t)H_ * W_);

  float acc[8] = {0.f, 0.f, 0.f, 0.f, 0.f, 0.f, 0.f, 0.f};
#pragma unroll
  for (int j = 0; j < 38; ++j) {
    const int yy = y0 - 15 + j;
    const float v = (yy >= 0 && yy < H_) ? tmp[base + (size_t)yy * W_ + x] : 0.f;
#pragma unroll
    for (int p = 0; p < 8; ++p) {
      const int c = j - p;                 // tap index for output row y0+p
      if (c >= 0 && c < 31) acc[p] += G[c] * v;
    }
  }
#pragma unroll
  for (int p = 0; p < 8; ++p) {
    const size_t idx = base + (size_t)(y0 + p) * W_ + x;
    const float il = __logf(1.f + ins[idx]);
    float r = __expf(il + acc[p]) - 1.f;
    r = fminf(fmaxf(r, 0.f), 1.f);
    out[idx] = r;
  }
}

extern "C" void kernel_launch(void* const* d_in, const int* in_sizes, int n_in,
                              void* d_out, int out_size, void* d_ws, size_t ws_size,
                              hipStream_t stream) {
  const float* bg  = (const float*)d_in[0];
  const float* ins = (const float*)d_in[1];
  float* out = (float*)d_out;

  const size_t need = (size_t)NROWS * W_ * sizeof(float);
  // tmp: prefer workspace; fallback overwrites bg (safe: hblur consumes each bg
  // row into LDS + __syncthreads before writing that row; rows are disjoint
  // across blocks; harness restores inputs before every launch).
  float* tmp = (ws_size >= need) ? (float*)d_ws : (float*)d_in[0];

  hblur<<<dim3(NROWS), dim3(128), 0, stream>>>(bg, ins, tmp);
  vblur<<<dim3(8, 16, NIMG), dim3(64, 4, 1), 0, stream>>>(tmp, ins, out);
}